// Round 7
// baseline (332.953 us; speedup 1.0000x reference)
//
#include <hip/hip_runtime.h>

// VQ-VAE vector quantization forward — MFMA fast-path + exact np recheck.
// x: [32,64,64,64] f32 -> flat [N=131072, D=64]; embeddings: [D=64, K=512].
//
// Exactness contract (validated rounds 2-6 at absmax 0.0): the chosen index
// per row must equal np's argmin over
//   dist_k = fl( fl(A + B_k) - fl(2*sim_k) ),  first-min tie-break,
// with A = np pairwise sum(f*f) (8-acc path), B_k = sequential sum(e*e),
// sim_k = sequential FMA chain over d. out = fl(x + fl(q-x));
// loss = 1.25*mean((q-x)^2).
//
// Round 7: the 4.3G MACs leave the VALU (structural floor ~77us) for MFMA:
//  - x = x1+x2, e = e1+e2 (bf16 RNE splits; residuals <= 2^-18).
//    sim~ = x1e1 + x1e2 + x2e1 via 6x mfma_f32_16x16x32_bf16 per 16x16 tile
//    (2 K-halves). |sim~ - sim_real| <= ~6e-5 worst row.
//  - argmin is invariant to the per-row constant A -> fast score
//    s_k = B_k - 2 sim~_k. Track (min1, idx1, min2) per row; margin
//    min2-min1 > 1e-3 >> 2*(eps_mfma + eps_npquant) proves idx1 == np argmin.
//  - Rows under margin (~0.7%) re-scanned in-block with the exact np code
//    (round-2 validated) incl. first-min tie -> every final index exact.
//  - Epilogue + loss: byte-identical round-6 code (validated).
// Fragment layouts (learn_hip m89/m120): A[m=lane&15][k=quad*8+j],
// B[k=quad*8+j][n=lane&15], C col=lane&15 row=quad*4+reg.

constexpr int D = 64;
constexpr int K = 512;
constexpr int NROWS = 131072;           // 32*64*64*64 / 64
constexpr long long NELEM = 8388608LL;  // NROWS * D
constexpr int RPB = 64;                 // rows per block
constexpr int FPAD = 65;                // LDS f32 row stride
constexpr float THRESH = 1e-3f;        // fast-path margin

typedef __attribute__((ext_vector_type(8))) short bf16x8;
typedef __attribute__((ext_vector_type(4))) float f32x4;

__device__ __forceinline__ unsigned short bf16_rne(float f) {
    unsigned int u = __float_as_uint(f);
    unsigned int r = u + 0x7fffu + ((u >> 16) & 1u);
    return (unsigned short)(r >> 16);
}
__device__ __forceinline__ float bf16_f(unsigned short h) {
    return __uint_as_float(((unsigned int)h) << 16);
}

// Prep: B_k = ||e_k||^2 np-exact (sequential mul+add over d) AND the bf16
// split tables eb1/eb2 laid out code-major [512][64] for direct B-frag loads.
__global__ __launch_bounds__(512) void vq_prep(const float* __restrict__ emb,
                                               float* __restrict__ e2,
                                               unsigned short* __restrict__ eb1,
                                               unsigned short* __restrict__ eb2,
                                               float* __restrict__ loss_acc) {
    const int k = threadIdx.x;  // 0..511 (one code per thread)
    float b = 0.f;
    bool first = true;
#pragma unroll 1
    for (int db = 0; db < D; db += 8) {
        float e[8];
#pragma unroll
        for (int j = 0; j < 8; ++j) e[j] = emb[(db + j) * K + k];  // coalesced
        // np axis-0 reduction: strictly sequential over d, separate mul+add
#pragma unroll
        for (int j = 0; j < 8; ++j) {
            float sq = __fmul_rn(e[j], e[j]);
            b = first ? sq : __fadd_rn(b, sq);
            first = false;
        }
        unsigned short t1[8], t2[8];
#pragma unroll
        for (int j = 0; j < 8; ++j) {
            t1[j] = bf16_rne(e[j]);
            t2[j] = bf16_rne(e[j] - bf16_f(t1[j]));  // e - e1 exact in f32
        }
        *reinterpret_cast<uint4*>(&eb1[k * D + db]) =
            *reinterpret_cast<const uint4*>(&t1[0]);
        *reinterpret_cast<uint4*>(&eb2[k * D + db]) =
            *reinterpret_cast<const uint4*>(&t2[0]);
    }
    e2[k] = b;
    if (k == 0) loss_acc[0] = 0.f;
}

__global__ __launch_bounds__(256) void vq_main(const float* __restrict__ x,
                                               const float* __restrict__ emb,
                                               const float* __restrict__ e2g,
                                               const unsigned short* __restrict__ eb1,
                                               const unsigned short* __restrict__ eb2,
                                               float* __restrict__ out,
                                               float* __restrict__ loss_acc) {
    const int tid = threadIdx.x;
    const int m = tid & 15;          // col-within-tile / row-within-wave-tile
    const int quad = (tid >> 4) & 3;
    const int wv = tid >> 6;         // wave: owns rows wv*16..wv*16+15

    __shared__ float sf[RPB * FPAD];  // x tile f32 (stride 65)
    __shared__ float e2l[K];          // ||e_k||^2
    __shared__ int bx[RPB];
    __shared__ float srv[256];
    __shared__ int sri[256];
    __shared__ float wsum[4];
    __shared__ int slow_n;

    if (tid == 0) slow_n = 0;
    // stage e2 (global ws -> LDS)
    e2l[tid] = e2g[tid];
    e2l[tid + 256] = e2g[tid + 256];

    // stage x tile: 64 rows x 16 float4, coalesced (round-6 validated)
    {
        const size_t base = (size_t)blockIdx.x * RPB * D;
#pragma unroll
        for (int j = 0; j < 4; ++j) {
            const int e4 = j * 256 + tid;
            const int rr = e4 >> 4;
            const int d0 = (e4 & 15) * 4;
            const float4 v =
                *reinterpret_cast<const float4*>(x + base + (size_t)rr * D + d0);
            float* p = &sf[rr * FPAD + d0];
            p[0] = v.x; p[1] = v.y; p[2] = v.z; p[3] = v.w;
        }
    }
    __syncthreads();

    // Build this lane's A-fragments (x1,x2 splits, both K-halves) from LDS.
    // A[m=lane&15][k=quad*8+j]; my row = wv*16 + m.
    bf16x8 a10, a11, a20, a21;
    {
        const float* fr = &sf[(wv * 16 + m) * FPAD];
        union { bf16x8 v; unsigned short u[8]; } u10, u11, u20, u21;
#pragma unroll
        for (int j = 0; j < 8; ++j) {
            float v0 = fr[quad * 8 + j];
            float v1 = fr[quad * 8 + j + 32];
            unsigned short h0 = bf16_rne(v0), h1 = bf16_rne(v1);
            u10.u[j] = h0; u11.u[j] = h1;
            u20.u[j] = bf16_rne(v0 - bf16_f(h0));
            u21.u[j] = bf16_rne(v1 - bf16_f(h1));
        }
        a10 = u10.v; a11 = u11.v; a20 = u20.v; a21 = u21.v;
    }

    // Tile loop: 32 tiles of 16 codes. B-frags from global split tables
    // (L2-resident, 16B/lane dwordx4). 6 MFMAs/tile.
    float m1[4], m2[4];
    int i1[4];
#pragma unroll
    for (int g = 0; g < 4; ++g) { m1[g] = 3.0e38f; m2[g] = 3.0e38f; i1[g] = 0; }

#pragma unroll 2
    for (int n0 = 0; n0 < K; n0 += 16) {
        const int col = n0 + m;
        const unsigned short* p1 = eb1 + col * D + quad * 8;
        const unsigned short* p2 = eb2 + col * D + quad * 8;
        bf16x8 b10 = *reinterpret_cast<const bf16x8*>(p1);
        bf16x8 b11 = *reinterpret_cast<const bf16x8*>(p1 + 32);
        bf16x8 b20 = *reinterpret_cast<const bf16x8*>(p2);
        bf16x8 b21 = *reinterpret_cast<const bf16x8*>(p2 + 32);
        f32x4 c = {0.f, 0.f, 0.f, 0.f};
        c = __builtin_amdgcn_mfma_f32_16x16x32_bf16(a10, b10, c, 0, 0, 0);
        c = __builtin_amdgcn_mfma_f32_16x16x32_bf16(a11, b11, c, 0, 0, 0);
        c = __builtin_amdgcn_mfma_f32_16x16x32_bf16(a20, b10, c, 0, 0, 0);
        c = __builtin_amdgcn_mfma_f32_16x16x32_bf16(a21, b11, c, 0, 0, 0);
        c = __builtin_amdgcn_mfma_f32_16x16x32_bf16(a10, b20, c, 0, 0, 0);
        c = __builtin_amdgcn_mfma_f32_16x16x32_bf16(a11, b21, c, 0, 0, 0);
        const float Bn = e2l[col];
#pragma unroll
        for (int g = 0; g < 4; ++g) {
            float s = fmaf(-2.f, c[g], Bn);
            bool lt1 = s < m1[g];
            m2[g] = lt1 ? m1[g] : (s < m2[g] ? s : m2[g]);
            if (lt1) { m1[g] = s; i1[g] = col; }
        }
    }

    // Cross-lane combine within each quad's 16 lanes (cols of the row group).
#pragma unroll
    for (int g = 0; g < 4; ++g) {
#pragma unroll
        for (int off = 1; off < 16; off <<= 1) {
            float o1 = __shfl_xor(m1[g], off, 64);
            int oi = __shfl_xor(i1[g], off, 64);
            float o2 = __shfl_xor(m2[g], off, 64);
            float nm2 = fminf(fmaxf(m1[g], o1), fminf(m2[g], o2));
            bool take = (o1 < m1[g]) || (o1 == m1[g] && oi < i1[g]);
            if (take) { m1[g] = o1; i1[g] = oi; }
            m2[g] = nm2;  // equal mins at diff idx -> gap 0 -> slow path
        }
        if (m == 0) {
            const int rl = wv * 16 + quad * 4 + g;  // row in block
            const bool fast = (m2[g] - m1[g]) > THRESH;
            bx[rl] = fast ? i1[g] : -1;
            if (!fast) atomicAdd(&slow_n, 1);
        }
    }
    __syncthreads();

    // Exact np recheck for under-margin rows (rare: ~0.7% of rows).
    if (slow_n > 0) {
#pragma unroll 1
        for (int rr = 0; rr < RPB; ++rr) {
            if (bx[rr] >= 0) continue;  // uniform (LDS broadcast)
            const float* fr2 = &sf[rr * FPAD];
            // A: np pairwise 8-accumulator path (round-2 validated)
            float r8[8];
#pragma unroll
            for (int j = 0; j < 8; ++j) r8[j] = __fmul_rn(fr2[j], fr2[j]);
#pragma unroll
            for (int i = 8; i < D; i += 8)
#pragma unroll
                for (int j = 0; j < 8; ++j)
                    r8[j] = __fadd_rn(r8[j], __fmul_rn(fr2[i + j], fr2[i + j]));
            const float A = __fadd_rn(
                __fadd_rn(__fadd_rn(r8[0], r8[1]), __fadd_rn(r8[2], r8[3])),
                __fadd_rn(__fadd_rn(r8[4], r8[5]), __fadd_rn(r8[6], r8[7])));
            // this thread: codes tid and tid+256, sequential FMA chain over d
            float acc0 = 0.f, acc1 = 0.f;
#pragma unroll
            for (int d = 0; d < D; ++d) {
                const float fd = fr2[d];  // LDS broadcast
                acc0 = __fmaf_rn(fd, emb[d * K + tid], acc0);
                acc1 = __fmaf_rn(fd, emb[d * K + tid + 256], acc1);
            }
            float d0 = __fsub_rn(__fadd_rn(A, e2l[tid]), __fmul_rn(2.f, acc0));
            float d1 = __fsub_rn(__fadd_rn(A, e2l[tid + 256]),
                                 __fmul_rn(2.f, acc1));
            float bv = d0; int bi = tid;
            if (d1 < bv) { bv = d1; bi = tid + 256; }  // tid < tid+256
            srv[tid] = bv; sri[tid] = bi;
            __syncthreads();
            for (int s2 = 128; s2 > 0; s2 >>= 1) {
                if (tid < s2) {
                    float ov = srv[tid + s2]; int oi = sri[tid + s2];
                    if (ov < srv[tid] || (ov == srv[tid] && oi < sri[tid])) {
                        srv[tid] = ov; sri[tid] = oi;
                    }
                }
                __syncthreads();
            }
            if (tid == 0) bx[rr] = sri[0];
            __syncthreads();
        }
    }

    // Epilogue + loss: byte-identical to round 6 (validated bit-exact).
    float lsum = 0.f;
#pragma unroll
    for (int j = 0; j < 4; ++j) {
        const int e4 = j * 256 + tid;
        const int rr2 = e4 >> 4;
        const int d0 = (e4 & 15) * 4;
        const size_t gbase = (size_t)(blockIdx.x * RPB + rr2) * D + d0;
        const float4 xv = *reinterpret_cast<const float4*>(x + gbase);
        const int bi = bx[rr2];
        const float* eq = emb + bi;
        float4 o;
        float qv, t;
        qv = eq[(d0 + 0) * K]; t = __fsub_rn(qv, xv.x);
        lsum = __fmaf_rn(t, t, lsum); o.x = __fadd_rn(xv.x, t);
        qv = eq[(d0 + 1) * K]; t = __fsub_rn(qv, xv.y);
        lsum = __fmaf_rn(t, t, lsum); o.y = __fadd_rn(xv.y, t);
        qv = eq[(d0 + 2) * K]; t = __fsub_rn(qv, xv.z);
        lsum = __fmaf_rn(t, t, lsum); o.z = __fadd_rn(xv.z, t);
        qv = eq[(d0 + 3) * K]; t = __fsub_rn(qv, xv.w);
        lsum = __fmaf_rn(t, t, lsum); o.w = __fadd_rn(xv.w, t);
        *reinterpret_cast<float4*>(out + gbase) = o;
    }
#pragma unroll
    for (int off = 32; off > 0; off >>= 1) lsum += __shfl_down(lsum, off, 64);
    if ((tid & 63) == 0) wsum[wv] = lsum;
    __syncthreads();
    if (tid == 0)
        atomicAdd(loss_acc, wsum[0] + wsum[1] + wsum[2] + wsum[3]);
}

__global__ void vq_finalize(const float* __restrict__ loss_acc,
                            float* __restrict__ out_loss) {
    if (threadIdx.x == 0) {
        float mm = loss_acc[0] / (float)NELEM;  // /2^23: exact
        out_loss[0] = 1.25f * mm;               // == fl(0.25m + m)
    }
}

extern "C" void kernel_launch(void* const* d_in, const int* in_sizes, int n_in,
                              void* d_out, int out_size, void* d_ws, size_t ws_size,
                              hipStream_t stream) {
    const float* x = (const float*)d_in[0];
    const float* emb = (const float*)d_in[1];
    float* out = (float*)d_out;

    // ws map: [0] loss_acc | +64 e2norm (512 f) | +1024B-aligned split tables
    float* ws = (float*)d_ws;
    float* loss_acc = ws;
    float* e2 = ws + 64;
    unsigned short* eb1 = (unsigned short*)(ws + 1024);        // 64 KB
    unsigned short* eb2 = eb1 + (size_t)K * D;                 // 64 KB

    vq_prep<<<1, 512, 0, stream>>>(emb, e2, eb1, eb2, loss_acc);
    vq_main<<<NROWS / RPB, 256, 0, stream>>>(x, emb, e2, eb1, eb2, out, loss_acc);
    vq_finalize<<<1, 64, 0, stream>>>(loss_acc, out + NELEM);
}

// Round 8
// 198.472 us; speedup vs baseline: 1.6776x; 1.6776x over previous
//
#include <hip/hip_runtime.h>

// VQ-VAE vector quantization forward — MFMA fast-path + exact np recheck.
// x: [32,64,64,64] f32 -> flat [N=131072, D=64]; embeddings: [D=64, K=512].
//
// Exactness contract (validated rounds 2-7 at absmax 0.0): chosen index per
// row == np argmin over dist_k = fl(fl(A+B_k) - fl(2*sim_k)), first-min tie;
// A = np pairwise 8-acc sum(f*f); B_k = sequential sum(e*e); sim = sequential
// FMA chain over d. out = fl(x + fl(q-x)); loss = 1.25*mean((q-x)^2).
//
// Round 8 — fix round-7's latency collapse (VGPR=160, occupancy 9%, B-frag
// gathers of 16 cache lines inside a 6-deep MFMA chain):
//  - ebf table pre-swizzled in prep to MFMA-fragment order: lane l's 16B at
//    base + l*16 -> one coalesced 1KB dwordx4 per fragment (L1-friendly).
//  - 8 MFMAs (adds x2*e2) as TWO independent 4-chains -> fast err ~1e-5,
//    margin 1e-3 has ~100x slack (1e-3 empirically validated in round 7 at
//    worse accuracy).
//  - 4 lean kernels: main (argmin -> bx + slow list), fix (wave-per-row exact
//    np rescan of flagged rows), epi (round-6-validated epilogue), finalize.
// Frag layouts (validated r7): A[m=lane&15][k=quad*8+j], B[k][n=m] with
// lane=quad*16+m, C col=lane&15 row=quad*4+reg.

constexpr int D = 64;
constexpr int K = 512;
constexpr int NROWS = 131072;
constexpr long long NELEM = 8388608LL;
constexpr int RPB = 64;
constexpr float THRESH = 1e-3f;
constexpr int SLOWCAP = 16384;

typedef __attribute__((ext_vector_type(8))) short bf16x8;
typedef __attribute__((ext_vector_type(4))) float f32x4;

__device__ __forceinline__ unsigned short bf16_rne(float f) {
    unsigned int u = __float_as_uint(f);
    unsigned int r = u + 0x7fffu + ((u >> 16) & 1u);
    return (unsigned short)(r >> 16);
}
__device__ __forceinline__ float bf16_f(unsigned short h) {
    return __uint_as_float(((unsigned int)h) << 16);
}

// ws map (float offsets): 0 loss | 1 cnt(int) | 64 e2[512] | 1024 ebf(128KB)
// | 34816 bx[131072](int) | 165888 slow[16384](int)

// Prep (8 blocks x 64): e2 np-exact + fragment-ordered bf16 split table.
// ebf[t*2048 + (half + 2*table)*512 + lane*8 + j], lane=q*16+m, value =
// split_{table}( e[d = q*8+j+32*half][c = t*16+m] ).
__global__ __launch_bounds__(64) void vq_prep(const float* __restrict__ emb,
                                              float* __restrict__ e2,
                                              unsigned short* __restrict__ ebf,
                                              float* __restrict__ loss_acc,
                                              int* __restrict__ cnt) {
    const int c = blockIdx.x * 64 + threadIdx.x;
    const int t = c >> 4, m = c & 15;
    float b = 0.f;
#pragma unroll
    for (int d = 0; d < D; ++d) {
        float e = emb[d * K + c];  // coalesced across 64 threads
        float sq = __fmul_rn(e, e);
        b = (d == 0) ? sq : __fadd_rn(b, sq);  // np axis-0 sequential order
        unsigned short h1 = bf16_rne(e);
        unsigned short h2 = bf16_rne(e - bf16_f(h1));
        const int q = (d >> 3) & 3, j = d & 7, half = d >> 5;
        const int base = t * 2048 + (q * 16 + m) * 8 + j;
        ebf[base + half * 512] = h1;
        ebf[base + 1024 + half * 512] = h2;
    }
    e2[c] = b;
    if (c == 0) { loss_acc[0] = 0.f; cnt[0] = 0; }
}

// Main: fast argmin via MFMA; writes bx[row] + flags under-margin rows.
__global__ __launch_bounds__(256, 4) void vq_main(
    const float* __restrict__ x, const float* __restrict__ e2g,
    const unsigned short* __restrict__ ebf, int* __restrict__ bx,
    int* __restrict__ slow, int* __restrict__ cnt) {
    const int tid = threadIdx.x;
    const int l = tid & 63;
    const int wv = tid >> 6;
    const int m = l & 15, q = l >> 4;

    // A-fragments straight from global (16 rows/wave, each lane 2x32B).
    bf16x8 a10, a11, a20, a21;
    {
        const float* xr =
            x + ((size_t)blockIdx.x * RPB + wv * 16 + m) * D + q * 8;
        float4 v0 = *reinterpret_cast<const float4*>(xr);
        float4 v1 = *reinterpret_cast<const float4*>(xr + 4);
        float4 v2 = *reinterpret_cast<const float4*>(xr + 32);
        float4 v3 = *reinterpret_cast<const float4*>(xr + 36);
        float h0[8] = {v0.x, v0.y, v0.z, v0.w, v1.x, v1.y, v1.z, v1.w};
        float h1f[8] = {v2.x, v2.y, v2.z, v2.w, v3.x, v3.y, v3.z, v3.w};
        union { bf16x8 v; unsigned short u[8]; } u10, u11, u20, u21;
#pragma unroll
        for (int j = 0; j < 8; ++j) {
            unsigned short p = bf16_rne(h0[j]), r = bf16_rne(h1f[j]);
            u10.u[j] = p; u11.u[j] = r;
            u20.u[j] = bf16_rne(h0[j] - bf16_f(p));
            u21.u[j] = bf16_rne(h1f[j] - bf16_f(r));
        }
        a10 = u10.v; a11 = u11.v; a20 = u20.v; a21 = u21.v;
    }

    float m1[4], m2[4];
    int i1[4];
#pragma unroll
    for (int g = 0; g < 4; ++g) { m1[g] = 3.0e38f; m2[g] = 3.0e38f; i1[g] = 0; }

#pragma unroll 2
    for (int t = 0; t < 32; ++t) {
        const unsigned short* tb = ebf + t * 2048 + l * 8;
        bf16x8 b10 = *reinterpret_cast<const bf16x8*>(tb);         // coalesced
        bf16x8 b11 = *reinterpret_cast<const bf16x8*>(tb + 512);   // 1KB/load
        bf16x8 b20 = *reinterpret_cast<const bf16x8*>(tb + 1024);
        bf16x8 b21 = *reinterpret_cast<const bf16x8*>(tb + 1536);
        const float Bn = e2g[t * 16 + m];
        f32x4 cp = {0.f, 0.f, 0.f, 0.f}, cq = {0.f, 0.f, 0.f, 0.f};
        // two independent 4-chains (full product incl. x2*e2)
        cp = __builtin_amdgcn_mfma_f32_16x16x32_bf16(a10, b10, cp, 0, 0, 0);
        cq = __builtin_amdgcn_mfma_f32_16x16x32_bf16(a20, b10, cq, 0, 0, 0);
        cp = __builtin_amdgcn_mfma_f32_16x16x32_bf16(a11, b11, cp, 0, 0, 0);
        cq = __builtin_amdgcn_mfma_f32_16x16x32_bf16(a21, b11, cq, 0, 0, 0);
        cp = __builtin_amdgcn_mfma_f32_16x16x32_bf16(a20, b20, cp, 0, 0, 0);
        cq = __builtin_amdgcn_mfma_f32_16x16x32_bf16(a10, b20, cq, 0, 0, 0);
        cp = __builtin_amdgcn_mfma_f32_16x16x32_bf16(a21, b21, cp, 0, 0, 0);
        cq = __builtin_amdgcn_mfma_f32_16x16x32_bf16(a11, b21, cq, 0, 0, 0);
        const int col = t * 16 + m;
#pragma unroll
        for (int g = 0; g < 4; ++g) {
            float s = fmaf(-2.f, cp[g] + cq[g], Bn);
            bool lt1 = s < m1[g];
            m2[g] = lt1 ? m1[g] : (s < m2[g] ? s : m2[g]);
            if (lt1) { m1[g] = s; i1[g] = col; }
        }
    }

    // Combine across the 16 lanes of each quad (validated round 7).
#pragma unroll
    for (int g = 0; g < 4; ++g) {
#pragma unroll
        for (int off = 1; off < 16; off <<= 1) {
            float o1 = __shfl_xor(m1[g], off, 64);
            int oi = __shfl_xor(i1[g], off, 64);
            float o2 = __shfl_xor(m2[g], off, 64);
            float nm2 = fminf(fmaxf(m1[g], o1), fminf(m2[g], o2));
            bool take = (o1 < m1[g]) || (o1 == m1[g] && oi < i1[g]);
            if (take) { m1[g] = o1; i1[g] = oi; }
            m2[g] = nm2;  // equal mins, diff idx -> gap 0 -> slow path
        }
        if (m == 0) {
            const int row = blockIdx.x * RPB + wv * 16 + q * 4 + g;
            bx[row] = i1[g];
            if (!((m2[g] - m1[g]) > THRESH)) {
                int p = atomicAdd(cnt, 1);
                if (p < SLOWCAP) slow[p] = row;
            }
        }
    }
}

// Fix: exact np rescan, one wave per flagged row (~1% of rows).
__global__ __launch_bounds__(256) void vq_fix(const float* __restrict__ x,
                                              const float* __restrict__ emb,
                                              const float* __restrict__ e2g,
                                              const int* __restrict__ slow,
                                              const int* __restrict__ cnt,
                                              int* __restrict__ bx) {
    int n = cnt[0];
    if (n > SLOWCAP) n = SLOWCAP;
    const int lane = threadIdx.x & 63;
    const int wg = blockIdx.x * 4 + (threadIdx.x >> 6);
#pragma unroll 1
    for (int i = wg; i < n; i += 128 * 4) {
        const int row = __builtin_amdgcn_readfirstlane(slow[i]);
        const float* fr = x + (size_t)row * D;  // uniform -> scalar loads
        // A: np pairwise 8-accumulator path (round-2 validated)
        float r8[8];
#pragma unroll
        for (int j = 0; j < 8; ++j) r8[j] = __fmul_rn(fr[j], fr[j]);
#pragma unroll
        for (int ii = 8; ii < D; ii += 8)
#pragma unroll
            for (int j = 0; j < 8; ++j)
                r8[j] = __fadd_rn(r8[j], __fmul_rn(fr[ii + j], fr[ii + j]));
        const float A = __fadd_rn(
            __fadd_rn(__fadd_rn(r8[0], r8[1]), __fadd_rn(r8[2], r8[3])),
            __fadd_rn(__fadd_rn(r8[4], r8[5]), __fadd_rn(r8[6], r8[7])));
        // 8 codes/lane (c = lane + 64u), sequential FMA chain over d each.
        float acc[8];
#pragma unroll
        for (int u = 0; u < 8; ++u) acc[u] = 0.f;
#pragma unroll
        for (int d = 0; d < D; ++d) {
            const float fd = fr[d];
#pragma unroll
            for (int u = 0; u < 8; ++u)
                acc[u] = __fmaf_rn(fd, emb[d * K + lane + 64 * u], acc[u]);
        }
        float bv = 3.0e38f;
        int bi = 0;
#pragma unroll
        for (int u = 0; u < 8; ++u) {
            const int c = lane + 64 * u;
            float dv = __fsub_rn(__fadd_rn(A, e2g[c]), __fmul_rn(2.f, acc[u]));
            if (dv < bv) { bv = dv; bi = c; }  // ascending c within lane
        }
#pragma unroll
        for (int off = 1; off < 64; off <<= 1) {
            float ov = __shfl_xor(bv, off, 64);
            int oi = __shfl_xor(bi, off, 64);
            if (ov < bv || (ov == bv && oi < bi)) { bv = ov; bi = oi; }
        }
        if (lane == 0) bx[row] = bi;
    }
}

// Epilogue: round-6-validated gather/write/loss, bx from global.
__global__ __launch_bounds__(256) void vq_epi(const float* __restrict__ x,
                                              const float* __restrict__ emb,
                                              const int* __restrict__ bx,
                                              float* __restrict__ out,
                                              float* __restrict__ loss_acc) {
    const int tid = threadIdx.x;
    __shared__ int bxl[RPB];
    __shared__ float wsum[4];
    if (tid < RPB) bxl[tid] = bx[blockIdx.x * RPB + tid];
    __syncthreads();
    float lsum = 0.f;
#pragma unroll
    for (int j = 0; j < 4; ++j) {
        const int e4 = j * 256 + tid;
        const int rr2 = e4 >> 4;
        const int d0 = (e4 & 15) * 4;
        const size_t gbase = (size_t)(blockIdx.x * RPB + rr2) * D + d0;
        const float4 xv = *reinterpret_cast<const float4*>(x + gbase);
        const float* eq = emb + bxl[rr2];
        float4 o;
        float qv, t;
        qv = eq[(d0 + 0) * K]; t = __fsub_rn(qv, xv.x);
        lsum = __fmaf_rn(t, t, lsum); o.x = __fadd_rn(xv.x, t);
        qv = eq[(d0 + 1) * K]; t = __fsub_rn(qv, xv.y);
        lsum = __fmaf_rn(t, t, lsum); o.y = __fadd_rn(xv.y, t);
        qv = eq[(d0 + 2) * K]; t = __fsub_rn(qv, xv.z);
        lsum = __fmaf_rn(t, t, lsum); o.z = __fadd_rn(xv.z, t);
        qv = eq[(d0 + 3) * K]; t = __fsub_rn(qv, xv.w);
        lsum = __fmaf_rn(t, t, lsum); o.w = __fadd_rn(xv.w, t);
        *reinterpret_cast<float4*>(out + gbase) = o;
    }
#pragma unroll
    for (int off = 32; off > 0; off >>= 1) lsum += __shfl_down(lsum, off, 64);
    if ((tid & 63) == 0) wsum[tid >> 6] = lsum;
    __syncthreads();
    if (tid == 0)
        atomicAdd(loss_acc, wsum[0] + wsum[1] + wsum[2] + wsum[3]);
}

__global__ void vq_finalize(const float* __restrict__ loss_acc,
                            float* __restrict__ out_loss) {
    if (threadIdx.x == 0) {
        float mm = loss_acc[0] / (float)NELEM;  // /2^23: exact
        out_loss[0] = 1.25f * mm;               // == fl(0.25m + m)
    }
}

extern "C" void kernel_launch(void* const* d_in, const int* in_sizes, int n_in,
                              void* d_out, int out_size, void* d_ws, size_t ws_size,
                              hipStream_t stream) {
    const float* x = (const float*)d_in[0];
    const float* emb = (const float*)d_in[1];
    float* out = (float*)d_out;

    float* ws = (float*)d_ws;
    float* loss_acc = ws;
    int* cnt = (int*)ws + 1;
    float* e2 = ws + 64;
    unsigned short* ebf = (unsigned short*)(ws + 1024);  // 128 KB
    int* bx = (int*)(ws + 34816);                        // 512 KB
    int* slow = (int*)(ws + 165888);                     // 64 KB

    vq_prep<<<8, 64, 0, stream>>>(emb, e2, ebf, loss_acc, cnt);
    vq_main<<<NROWS / RPB, 256, 0, stream>>>(x, e2, ebf, bx, slow, cnt);
    vq_fix<<<128, 256, 0, stream>>>(x, emb, e2, slow, cnt, bx);
    vq_epi<<<NROWS / RPB, 256, 0, stream>>>(x, emb, bx, out, loss_acc);
    vq_finalize<<<1, 64, 0, stream>>>(loss_acc, out + NELEM);
}